// Round 13
// baseline (163.237 us; speedup 1.0000x reference)
//
#include <hip/hip_runtime.h>
#include <math.h>

// Sparse EdgeConvE round 13: 3 dispatches, one block per node.
//   h1 = relu( U[i] + V[j] + e_ij @ We ),  U = x@(Wxi-Wxj)+ba, V = x@Wxj
//   out[i] = sum_j relu( h1 @ Wb + bb )
// K1 scan: row scan -> jl/cnt; e-gather (depth 2) -> ew1/ew2; U1/V1; Wb pack.
// K2 conv1+uv2: block i builds full x1 row in LDS (phase A depth-1, phase B
//   per-wave col-strip MFMA with register accumulation over row tiles), then
//   U2/V2 GEMV in-block. No partials, no atomics, no round-trip.
// K3 conv2+head: same, then W3/W4 head + sigmoid -> out[i].

#define NN 768
#define FF 64
#define DE 32
#define HH 64
#define CAP 128            // per-row edge capacity (deg ~38 +- 6)
#define SH1S 72            // padded bf16 LDS row stride

using bf16x8 = __attribute__((ext_vector_type(8))) short;
using f32x4  = __attribute__((ext_vector_type(4))) float;

__device__ __forceinline__ short f2b(float f) {
  unsigned u = __float_as_uint(f);
  return (short)((u + 0x7fffu + ((u >> 16) & 1u)) >> 16);   // RNE
}

// ---- K1: scan + e-gather + ew1/ew2 + U1/V1 + Wb pack ----
__global__ __launch_bounds__(256) void scan_kernel(
    const float* __restrict__ A, const float* __restrict__ x,
    const float* __restrict__ e,
    const float* __restrict__ W, const float* __restrict__ bias,   // W1a,b1a
    const float* __restrict__ We1, const float* __restrict__ We2,
    const float* __restrict__ Wb1, const float* __restrict__ Wb2,
    int* __restrict__ cnt, int* __restrict__ jl,
    float* __restrict__ U, float* __restrict__ V,
    float* __restrict__ ew1, float* __restrict__ ew2,
    short* __restrict__ Wbp1, short* __restrict__ Wbp2)
{
  const int i = blockIdx.x;
  const int tid = threadIdx.x;
  __shared__ int s_cnt;
  __shared__ int s_j[CAP];
  __shared__ float sx[64];
  __shared__ float su[4][64], sv[4][64];
  __shared__ __align__(16) float es[CAP][DE];   // 16 KB gathered e rows

  if (tid == 0) s_cnt = 0;
  __syncthreads();
  if (tid < 64) sx[tid] = x[i * 64 + tid];
  if (tid < NN / 4) {
    float4 a = ((const float4*)(A + i * NN))[tid];
    if (a.x != 0.0f) { int p = atomicAdd(&s_cnt, 1); if (p < CAP) s_j[p] = tid * 4 + 0; }
    if (a.y != 0.0f) { int p = atomicAdd(&s_cnt, 1); if (p < CAP) s_j[p] = tid * 4 + 1; }
    if (a.z != 0.0f) { int p = atomicAdd(&s_cnt, 1); if (p < CAP) s_j[p] = tid * 4 + 2; }
    if (a.w != 0.0f) { int p = atomicAdd(&s_cnt, 1); if (p < CAP) s_j[p] = tid * 4 + 3; }
  }
  __syncthreads();
  const int c = min(s_cnt, CAP);

  // gather e rows into LDS: 8 threads per slot (128 B each)
  for (int slot = tid >> 3; slot < c; slot += 32) {
    const int j = s_j[slot];
    ((float4*)es[slot])[tid & 7] =
        ((const float4*)(e + ((size_t)i * NN + j) * DE))[tid & 7];
  }

  const int c64 = tid & 63, sg = tid >> 6;
  float w1[DE], w2[DE];
#pragma unroll
  for (int d = 0; d < DE; ++d) { w1[d] = We1[d * HH + c64]; w2[d] = We2[d * HH + c64]; }
  __syncthreads();

  for (int slot = sg; slot < c; slot += 4) {
    float a1 = 0.0f, a2 = 0.0f;
#pragma unroll
    for (int d = 0; d < DE; ++d) {
      const float f = es[slot][d];        // wave-uniform LDS broadcast
      a1 = fmaf(f, w1[d], a1);
      a2 = fmaf(f, w2[d], a2);
    }
    ew1[((size_t)(i << 7) + slot) * HH + c64] = a1;
    ew2[((size_t)(i << 7) + slot) * HH + c64] = a2;
  }

  {  // U1/V1 partials
    float u = 0.0f, v = 0.0f;
#pragma unroll
    for (int t = 0; t < 16; ++t) {
      const int d = sg * 16 + t;
      const float xv = sx[d];
      const float wxi = W[d * 64 + c64];
      const float wxj = W[(64 + d) * 64 + c64];
      u = fmaf(xv, wxi - wxj, u);
      v = fmaf(xv, wxj, v);
    }
    su[sg][c64] = u; sv[sg][c64] = v;
  }

  if (i < 2) {  // pack Wb into bf16 B-fragment order
    const float* src = (i == 0) ? Wb1 : Wb2;
    short* dst = (i == 0) ? Wbp1 : Wbp2;
    for (int L = tid; L < 4096; L += 256) {
      const int j = L & 7, n = (L >> 3) & 15, quad = (L >> 7) & 3;
      const int kb = (L >> 9) & 1, ct = L >> 10;
      dst[L] = f2b(src[(kb * 32 + quad * 8 + j) * 64 + ct * 16 + n]);
    }
  }
  __syncthreads();

  if (tid < 64) {
    U[i * 64 + tid] = su[0][tid] + su[1][tid] + su[2][tid] + su[3][tid] + bias[tid];
    V[i * 64 + tid] = sv[0][tid] + sv[1][tid] + sv[2][tid] + sv[3][tid];
  }
  if (tid == 0) cnt[i] = c;
  for (int t = tid; t < c; t += 256) jl[(i << 7) + t] = s_j[t];
}

// ---- shared conv body: builds xrow[64] (fp32) in LDS for node i ----
// phase A: sh1b[slot] = bf16(relu(U[i]+V[j]+ew[i,slot])), zero pad rows.
// phase B: wave w owns channels w*16..w*16+15; loops row tiles, 2 MFMA each,
// accumulates masked relu(acc+bias) in registers; shfl-reduce; xrow store.
__device__ __forceinline__ void conv_body(
    int i, int c, const int* __restrict__ jl,
    const float* __restrict__ U, const float* __restrict__ V,
    const float* __restrict__ ew, const short* __restrict__ Wbp,
    const float* __restrict__ bb, short* sh1b, float* xrow,
    int tid, int lane, int wv)
{
  const int nt = (c + 15) >> 4;
  const int cpad = nt << 4;

  if (c > 0) {
    const float u_i = U[(i << 6) + lane];
    for (int slot = wv; slot < cpad; slot += 4) {
      short val = 0;
      if (slot < c) {
        const int j = jl[(i << 7) + slot];
        const float h = u_i + V[(j << 6) + lane]
                      + ew[((size_t)(i << 7) + slot) * HH + lane];
        val = f2b(fmaxf(h, 0.0f));
      }
      sh1b[slot * SH1S + lane] = val;
    }
  }
  __syncthreads();

  if (c > 0) {
    const int q = lane >> 4, n = lane & 15;
    bf16x8 b0 = *(const bf16x8*)(Wbp + (((wv * 2 + 0) * 4 + q) * 16 + n) * 8);
    bf16x8 b1 = *(const bf16x8*)(Wbp + (((wv * 2 + 1) * 4 + q) * 16 + n) * 8);
    const float bias = bb[wv * 16 + n];
    float s = 0.0f;
    for (int rt = 0; rt < nt; ++rt) {
      const short* sa = sh1b + (rt * 16 + n) * SH1S + q * 8;
      bf16x8 a0 = *(const bf16x8*)(sa);
      bf16x8 a1 = *(const bf16x8*)(sa + 32);
      f32x4 acc = {0.f, 0.f, 0.f, 0.f};
      acc = __builtin_amdgcn_mfma_f32_16x16x32_bf16(a0, b0, acc, 0, 0, 0);
      acc = __builtin_amdgcn_mfma_f32_16x16x32_bf16(a1, b1, acc, 0, 0, 0);
#pragma unroll
      for (int reg = 0; reg < 4; ++reg) {
        const int row = rt * 16 + q * 4 + reg;
        const float v = fmaxf(acc[reg] + bias, 0.0f);
        s += (row < c) ? v : 0.0f;
      }
    }
    s += __shfl_down(s, 32);
    s += __shfl_down(s, 16);
    if (lane < 16) xrow[wv * 16 + lane] = s;
  } else {
    if (lane < 16) xrow[wv * 16 + lane] = 0.0f;
  }
  __syncthreads();
}

// ---- K2: conv1 + U2/V2 in-block ----
__global__ __launch_bounds__(256) void conv1uv2_kernel(
    const int* __restrict__ cnt, const int* __restrict__ jl,
    const float* __restrict__ U1, const float* __restrict__ V1,
    const float* __restrict__ ew1, const short* __restrict__ Wbp1,
    const float* __restrict__ b1b,
    const float* __restrict__ W2a, const float* __restrict__ b2a,
    float* __restrict__ U2, float* __restrict__ V2)
{
  const int i = blockIdx.x;
  const int tid = threadIdx.x, lane = tid & 63, wv = tid >> 6;
  __shared__ __align__(16) short sh1b[CAP * SH1S];   // 18 KB
  __shared__ float xrow[64];
  __shared__ float su[4][64], sv[4][64];

  conv_body(i, cnt[i], jl, U1, V1, ew1, Wbp1, b1b, sh1b, xrow, tid, lane, wv);

  // U2/V2 GEMV from xrow
  const int c64 = tid & 63, qr = tid >> 6;
  {
    float u = 0.0f, v = 0.0f;
#pragma unroll
    for (int t = 0; t < 16; ++t) {
      const int d = qr * 16 + t;
      const float xv = xrow[d];
      const float wxi = W2a[d * 64 + c64];
      const float wxj = W2a[(64 + d) * 64 + c64];
      u = fmaf(xv, wxi - wxj, u);
      v = fmaf(xv, wxj, v);
    }
    su[qr][c64] = u; sv[qr][c64] = v;
  }
  __syncthreads();
  if (tid < 64) {
    U2[i * 64 + tid] = su[0][tid] + su[1][tid] + su[2][tid] + su[3][tid] + b2a[tid];
    V2[i * 64 + tid] = sv[0][tid] + sv[1][tid] + sv[2][tid] + sv[3][tid];
  }
}

// ---- K3: conv2 + MLP head ----
__global__ __launch_bounds__(256) void conv2head_kernel(
    const int* __restrict__ cnt, const int* __restrict__ jl,
    const float* __restrict__ U2, const float* __restrict__ V2,
    const float* __restrict__ ew2, const short* __restrict__ Wbp2,
    const float* __restrict__ b2b,
    const float* __restrict__ W3, const float* __restrict__ b3,
    const float* __restrict__ W4, const float* __restrict__ b4,
    float* __restrict__ out)
{
  const int i = blockIdx.x;
  const int tid = threadIdx.x, lane = tid & 63, wv = tid >> 6;
  __shared__ __align__(16) short sh1b[CAP * SH1S];
  __shared__ float xrow[64];
  __shared__ float sred[2];

  conv_body(i, cnt[i], jl, U2, V2, ew2, Wbp2, b2b, sh1b, xrow, tid, lane, wv);

  // head: relu(xrow @ W3 + b3) @ W4 + b4 -> sigmoid
  if (tid < 128) {
    float p = b3[tid];
#pragma unroll
    for (int c = 0; c < 64; ++c) p = fmaf(xrow[c], W3[c * 128 + tid], p);
    p = fmaxf(p, 0.0f);
    float v = p * W4[tid];
    v += __shfl_down(v, 32);
    v += __shfl_down(v, 16);
    v += __shfl_down(v, 8);
    v += __shfl_down(v, 4);
    v += __shfl_down(v, 2);
    v += __shfl_down(v, 1);
    if (lane == 0) sred[wv] = v;
  }
  __syncthreads();
  if (tid == 0) {
    const float z = sred[0] + sred[1] + b4[0];
    out[i] = 1.0f / (1.0f + expf(-z));
  }
}

extern "C" void kernel_launch(void* const* d_in, const int* in_sizes, int n_in,
                              void* d_out, int out_size, void* d_ws, size_t ws_size,
                              hipStream_t stream) {
  const float* A   = (const float*)d_in[0];
  const float* x   = (const float*)d_in[1];
  const float* e   = (const float*)d_in[2];
  const float* W1a = (const float*)d_in[3];
  const float* b1a = (const float*)d_in[4];
  const float* W1b = (const float*)d_in[5];
  const float* b1b = (const float*)d_in[6];
  const float* W2a = (const float*)d_in[7];
  const float* b2a = (const float*)d_in[8];
  const float* W2b = (const float*)d_in[9];
  const float* b2b = (const float*)d_in[10];
  const float* W3  = (const float*)d_in[11];
  const float* b3  = (const float*)d_in[12];
  const float* W4  = (const float*)d_in[13];
  const float* b4  = (const float*)d_in[14];
  float* out = (float*)d_out;

  // ws: [cnt | jl | U1 V1 U2 V2 | ew1 ew2 | Wbp1 Wbp2]
  int*   cnt  = (int*)d_ws;
  int*   jl   = cnt + NN;                            // 768*128
  float* U1   = (float*)(jl + NN * CAP);
  float* V1   = U1 + NN * HH;
  float* U2   = V1 + NN * HH;
  float* V2   = U2 + NN * HH;
  float* ew1  = V2 + NN * HH;                        // 768*128*64 each
  float* ew2  = ew1 + (size_t)NN * CAP * HH;
  short* Wbp1 = (short*)(ew2 + (size_t)NN * CAP * HH);
  short* Wbp2 = Wbp1 + 4096;

  scan_kernel<<<NN, 256, 0, stream>>>(A, x, e, W1a, b1a,
                                      W1a + 128 * HH, W2a + 128 * HH,
                                      W1b, W2b,
                                      cnt, jl, U1, V1, ew1, ew2, Wbp1, Wbp2);
  conv1uv2_kernel<<<NN, 256, 0, stream>>>(cnt, jl, U1, V1, ew1, Wbp1, b1b,
                                          W2a, b2a, U2, V2);
  conv2head_kernel<<<NN, 256, 0, stream>>>(cnt, jl, U2, V2, ew2, Wbp2, b2b,
                                           W3, b3, W4, b4, out);
}

// Round 14
// 153.039 us; speedup vs baseline: 1.0666x; 1.0666x over previous
//
#include <hip/hip_runtime.h>
#include <math.h>

// Sparse EdgeConvE round 14: ew1 never materialized (computed in-LDS in K2);
// ew2 stored bf16. 3 dispatches, one block per node.
//   h1 = relu( U[i] + V[j] + e_ij @ We ),  U = x@(Wxi-Wxj)+ba, V = x@Wxj
//   out[i] = sum_j relu( h1 @ Wb + bb )
// K1: A-row scan -> cnt/jl; U1/V1; Wb pack.
// K2: gather e rows (LDS) -> h1 = U1[i]+V1[j]+e@We1 directly; ew2=e@We2 ->
//     bf16 global (for K3); phase B MFMA -> x1 row; U2/V2 GEMV in-block.
// K3: h1 = U2[i]+V2[j]+ew2(bf16); phase B MFMA -> x2 row; W3/W4 head.

#define NN 768
#define FF 64
#define DE 32
#define HH 64
#define CAP 128            // per-row edge capacity (deg ~38 +- 6)
#define SH1S 72            // padded bf16 LDS row stride

using bf16x8 = __attribute__((ext_vector_type(8))) short;
using f32x4  = __attribute__((ext_vector_type(4))) float;

__device__ __forceinline__ short f2b(float f) {
  unsigned u = __float_as_uint(f);
  return (short)((u + 0x7fffu + ((u >> 16) & 1u)) >> 16);   // RNE
}
__device__ __forceinline__ float b2f(unsigned short u) {
  return __uint_as_float(((unsigned)u) << 16);
}

// ---- phase B (shared): H1[cpad x 64]bf16 @ Wb -> xrow[64], masked row sum ----
__device__ __forceinline__ void phaseB(
    const short* sh1b, const short* __restrict__ Wbp,
    const float* __restrict__ bb, float* xrow, int c, int lane, int wv)
{
  if (c > 0) {
    const int nt = (c + 15) >> 4;
    const int q = lane >> 4, n = lane & 15;
    bf16x8 b0 = *(const bf16x8*)(Wbp + (((wv * 2 + 0) * 4 + q) * 16 + n) * 8);
    bf16x8 b1 = *(const bf16x8*)(Wbp + (((wv * 2 + 1) * 4 + q) * 16 + n) * 8);
    const float bias = bb[wv * 16 + n];
    float s = 0.0f;
    for (int rt = 0; rt < nt; ++rt) {
      const short* sa = sh1b + (rt * 16 + n) * SH1S + q * 8;
      bf16x8 a0 = *(const bf16x8*)(sa);
      bf16x8 a1 = *(const bf16x8*)(sa + 32);
      f32x4 acc = {0.f, 0.f, 0.f, 0.f};
      acc = __builtin_amdgcn_mfma_f32_16x16x32_bf16(a0, b0, acc, 0, 0, 0);
      acc = __builtin_amdgcn_mfma_f32_16x16x32_bf16(a1, b1, acc, 0, 0, 0);
#pragma unroll
      for (int reg = 0; reg < 4; ++reg) {
        const int row = rt * 16 + q * 4 + reg;
        const float v = fmaxf(acc[reg] + bias, 0.0f);
        s += (row < c) ? v : 0.0f;
      }
    }
    s += __shfl_down(s, 32);
    s += __shfl_down(s, 16);
    if (lane < 16) xrow[wv * 16 + lane] = s;
  } else {
    if (lane < 16) xrow[wv * 16 + lane] = 0.0f;
  }
}

// ---- K1: scan + U1/V1 + Wb pack (no e access) ----
__global__ __launch_bounds__(256) void scan_kernel(
    const float* __restrict__ A, const float* __restrict__ x,
    const float* __restrict__ W, const float* __restrict__ bias,   // W1a,b1a
    const float* __restrict__ Wb1, const float* __restrict__ Wb2,
    int* __restrict__ cnt, int* __restrict__ jl,
    float* __restrict__ U, float* __restrict__ V,
    short* __restrict__ Wbp1, short* __restrict__ Wbp2)
{
  const int i = blockIdx.x;
  const int tid = threadIdx.x;
  __shared__ int s_cnt;
  __shared__ int s_j[CAP];
  __shared__ float sx[64];
  __shared__ float su[4][64], sv[4][64];

  if (tid == 0) s_cnt = 0;
  __syncthreads();
  if (tid < 64) sx[tid] = x[i * 64 + tid];
  if (tid < NN / 4) {
    float4 a = ((const float4*)(A + i * NN))[tid];
    if (a.x != 0.0f) { int p = atomicAdd(&s_cnt, 1); if (p < CAP) s_j[p] = tid * 4 + 0; }
    if (a.y != 0.0f) { int p = atomicAdd(&s_cnt, 1); if (p < CAP) s_j[p] = tid * 4 + 1; }
    if (a.z != 0.0f) { int p = atomicAdd(&s_cnt, 1); if (p < CAP) s_j[p] = tid * 4 + 2; }
    if (a.w != 0.0f) { int p = atomicAdd(&s_cnt, 1); if (p < CAP) s_j[p] = tid * 4 + 3; }
  }

  if (i < 2) {  // pack Wb into bf16 B-fragment order
    const float* src = (i == 0) ? Wb1 : Wb2;
    short* dst = (i == 0) ? Wbp1 : Wbp2;
    for (int L = tid; L < 4096; L += 256) {
      const int j = L & 7, n = (L >> 3) & 15, quad = (L >> 7) & 3;
      const int kb = (L >> 9) & 1, ct = L >> 10;
      dst[L] = f2b(src[(kb * 32 + quad * 8 + j) * 64 + ct * 16 + n]);
    }
  }
  __syncthreads();
  const int c = min(s_cnt, CAP);

  const int c64 = tid & 63, sg = tid >> 6;
  {  // U1/V1 partials
    float u = 0.0f, v = 0.0f;
#pragma unroll
    for (int t = 0; t < 16; ++t) {
      const int d = sg * 16 + t;
      const float xv = sx[d];
      const float wxi = W[d * 64 + c64];
      const float wxj = W[(64 + d) * 64 + c64];
      u = fmaf(xv, wxi - wxj, u);
      v = fmaf(xv, wxj, v);
    }
    su[sg][c64] = u; sv[sg][c64] = v;
  }
  __syncthreads();

  if (tid < 64) {
    U[i * 64 + tid] = su[0][tid] + su[1][tid] + su[2][tid] + su[3][tid] + bias[tid];
    V[i * 64 + tid] = sv[0][tid] + sv[1][tid] + sv[2][tid] + sv[3][tid];
  }
  if (tid == 0) cnt[i] = c;
  for (int t = tid; t < c; t += 256) jl[(i << 7) + t] = s_j[t];
}

// ---- K2: conv1 (in-LDS e) + ew2(bf16) + U2/V2 ----
__global__ __launch_bounds__(256) void conv1uv2_kernel(
    const int* __restrict__ cnt, const int* __restrict__ jl,
    const float* __restrict__ e,
    const float* __restrict__ U1, const float* __restrict__ V1,
    const float* __restrict__ We1, const float* __restrict__ We2,
    const short* __restrict__ Wbp1, const float* __restrict__ b1b,
    const float* __restrict__ W2a, const float* __restrict__ b2a,
    float* __restrict__ U2, float* __restrict__ V2,
    unsigned short* __restrict__ ew2b)
{
  const int i = blockIdx.x;
  const int tid = threadIdx.x, lane = tid & 63, wv = tid >> 6;
  __shared__ __align__(16) float es[CAP][DE];       // 16 KB
  __shared__ __align__(16) short sh1b[CAP * SH1S];  // 18 KB
  __shared__ int s_j[CAP];
  __shared__ float xrow[64];
  __shared__ float su[4][64], sv[4][64];

  const int c = cnt[i];
  for (int t = tid; t < c; t += 256) s_j[t] = jl[(i << 7) + t];
  __syncthreads();

  // gather e rows: 8 threads per slot (128 B each)
  for (int slot = tid >> 3; slot < c; slot += 32) {
    const int j = s_j[slot];
    ((float4*)es[slot])[tid & 7] =
        ((const float4*)(e + ((size_t)i * NN + j) * DE))[tid & 7];
  }

  // per-lane We columns (channel = lane)
  float w1e[DE], w2e[DE];
#pragma unroll
  for (int d = 0; d < DE; ++d) { w1e[d] = We1[d * HH + lane]; w2e[d] = We2[d * HH + lane]; }
  __syncthreads();

  // phase A: h1 rows + ew2 store (bf16)
  if (c > 0) {
    const int cpad = ((c + 15) >> 4) << 4;
    const float u_i = U1[(i << 6) + lane];
    for (int slot = wv; slot < cpad; slot += 4) {
      short val = 0;
      if (slot < c) {
        const int j = s_j[slot];
        float h = u_i + V1[(j << 6) + lane];
        float g = 0.0f;
#pragma unroll
        for (int d = 0; d < DE; ++d) {
          const float f = es[slot][d];   // wave-uniform LDS broadcast
          h = fmaf(f, w1e[d], h);
          g = fmaf(f, w2e[d], g);
        }
        val = f2b(fmaxf(h, 0.0f));
        ew2b[((size_t)(i << 7) + slot) * HH + lane] = (unsigned short)f2b(g);
      }
      sh1b[slot * SH1S + lane] = val;
    }
  }
  __syncthreads();

  phaseB(sh1b, Wbp1, b1b, xrow, c, lane, wv);
  __syncthreads();

  // U2/V2 GEMV from xrow
  const int c64 = tid & 63, qr = tid >> 6;
  {
    float u = 0.0f, v = 0.0f;
#pragma unroll
    for (int t = 0; t < 16; ++t) {
      const int d = qr * 16 + t;
      const float xv = xrow[d];
      const float wxi = W2a[d * 64 + c64];
      const float wxj = W2a[(64 + d) * 64 + c64];
      u = fmaf(xv, wxi - wxj, u);
      v = fmaf(xv, wxj, v);
    }
    su[qr][c64] = u; sv[qr][c64] = v;
  }
  __syncthreads();
  if (tid < 64) {
    U2[i * 64 + tid] = su[0][tid] + su[1][tid] + su[2][tid] + su[3][tid] + b2a[tid];
    V2[i * 64 + tid] = sv[0][tid] + sv[1][tid] + sv[2][tid] + sv[3][tid];
  }
}

// ---- K3: conv2 (ew2 bf16) + MLP head ----
__global__ __launch_bounds__(256) void conv2head_kernel(
    const int* __restrict__ cnt, const int* __restrict__ jl,
    const float* __restrict__ U2, const float* __restrict__ V2,
    const unsigned short* __restrict__ ew2b, const short* __restrict__ Wbp2,
    const float* __restrict__ b2b,
    const float* __restrict__ W3, const float* __restrict__ b3,
    const float* __restrict__ W4, const float* __restrict__ b4,
    float* __restrict__ out)
{
  const int i = blockIdx.x;
  const int tid = threadIdx.x, lane = tid & 63, wv = tid >> 6;
  __shared__ __align__(16) short sh1b[CAP * SH1S];
  __shared__ float xrow[64];
  __shared__ float sred[2];

  const int c = cnt[i];
  if (c > 0) {
    const int cpad = ((c + 15) >> 4) << 4;
    const float u_i = U2[(i << 6) + lane];
    for (int slot = wv; slot < cpad; slot += 4) {
      short val = 0;
      if (slot < c) {
        const int j = jl[(i << 7) + slot];
        const float h = u_i + V2[(j << 6) + lane]
                      + b2f(ew2b[((size_t)(i << 7) + slot) * HH + lane]);
        val = f2b(fmaxf(h, 0.0f));
      }
      sh1b[slot * SH1S + lane] = val;
    }
  }
  __syncthreads();

  phaseB(sh1b, Wbp2, b2b, xrow, c, lane, wv);
  __syncthreads();

  // head: relu(xrow @ W3 + b3) @ W4 + b4 -> sigmoid
  if (tid < 128) {
    float p = b3[tid];
#pragma unroll
    for (int cc = 0; cc < 64; ++cc) p = fmaf(xrow[cc], W3[cc * 128 + tid], p);
    p = fmaxf(p, 0.0f);
    float v = p * W4[tid];
    v += __shfl_down(v, 32);
    v += __shfl_down(v, 16);
    v += __shfl_down(v, 8);
    v += __shfl_down(v, 4);
    v += __shfl_down(v, 2);
    v += __shfl_down(v, 1);
    if (lane == 0) sred[wv] = v;
  }
  __syncthreads();
  if (tid == 0) {
    const float z = sred[0] + sred[1] + b4[0];
    out[i] = 1.0f / (1.0f + expf(-z));
  }
}

extern "C" void kernel_launch(void* const* d_in, const int* in_sizes, int n_in,
                              void* d_out, int out_size, void* d_ws, size_t ws_size,
                              hipStream_t stream) {
  const float* A   = (const float*)d_in[0];
  const float* x   = (const float*)d_in[1];
  const float* e   = (const float*)d_in[2];
  const float* W1a = (const float*)d_in[3];
  const float* b1a = (const float*)d_in[4];
  const float* W1b = (const float*)d_in[5];
  const float* b1b = (const float*)d_in[6];
  const float* W2a = (const float*)d_in[7];
  const float* b2a = (const float*)d_in[8];
  const float* W2b = (const float*)d_in[9];
  const float* b2b = (const float*)d_in[10];
  const float* W3  = (const float*)d_in[11];
  const float* b3  = (const float*)d_in[12];
  const float* W4  = (const float*)d_in[13];
  const float* b4  = (const float*)d_in[14];
  float* out = (float*)d_out;

  // ws: [cnt | jl | U1 V1 U2 V2 | ew2b(bf16) | Wbp1 Wbp2]
  int*   cnt  = (int*)d_ws;
  int*   jl   = cnt + NN;                            // 768*128
  float* U1   = (float*)(jl + NN * CAP);
  float* V1   = U1 + NN * HH;
  float* U2   = V1 + NN * HH;
  float* V2   = U2 + NN * HH;
  unsigned short* ew2b = (unsigned short*)(V2 + NN * HH);  // 768*128*64 u16
  short* Wbp1 = (short*)(ew2b + (size_t)NN * CAP * HH);
  short* Wbp2 = Wbp1 + 4096;

  scan_kernel<<<NN, 256, 0, stream>>>(A, x, W1a, b1a, W1b, W2b,
                                      cnt, jl, U1, V1, Wbp1, Wbp2);
  conv1uv2_kernel<<<NN, 256, 0, stream>>>(cnt, jl, e, U1, V1,
                                          W1a + 128 * HH, W2a + 128 * HH,
                                          Wbp1, b1b, W2a, b2a, U2, V2, ew2b);
  conv2head_kernel<<<NN, 256, 0, stream>>>(cnt, jl, U2, V2, ew2b, Wbp2, b2b,
                                           W3, b3, W4, b4, out);
}

// Round 15
// 149.905 us; speedup vs baseline: 1.0889x; 1.0209x over previous
//
#include <hip/hip_runtime.h>
#include <math.h>

// Sparse EdgeConvE round 15: phase A e@We moved to MFMA; ew2 round-trip
// eliminated (K3 re-gathers e, L2-warm). 3 dispatches, one block per node.
//   h1 = relu( U[i] + V[j] + e_ij @ We ),  U = x@(Wxi-Wxj)+ba, V = x@Wxj
//   out[i] = sum_j relu( h1 @ Wb + bb )
// K1: A-row scan -> cnt/jl; U1/V1; pack Wb (64x64) and We (32x64) to bf16
//     MFMA B-fragment order.
// K2: gather e -> bf16 LDS; P = E@We1 via 1 MFMA/row-tile; h1 = relu(U1[i]
//     + V1[j] + P) built in C-layout; phase B MFMA -> x1 row; U2/V2 GEMV.
// K3: same with We2/U2/V2, then W3/W4 head + sigmoid.

#define NN 768
#define FF 64
#define DE 32
#define HH 64
#define CAP 128            // per-row edge capacity (deg ~38 +- 6)
#define SH1S 72            // padded bf16 LDS row stride

using bf16x8 = __attribute__((ext_vector_type(8))) short;
using f32x4  = __attribute__((ext_vector_type(4))) float;

__device__ __forceinline__ short f2b(float f) {
  unsigned u = __float_as_uint(f);
  return (short)((u + 0x7fffu + ((u >> 16) & 1u)) >> 16);   // RNE
}

// ---- phase B (shared): H1[cpad x 64]bf16 @ Wb -> xrow[64], masked row sum ----
__device__ __forceinline__ void phaseB(
    const short* sh1b, const short* __restrict__ Wbp,
    const float* __restrict__ bb, float* xrow, int c, int lane, int wv)
{
  if (c > 0) {
    const int nt = (c + 15) >> 4;
    const int q = lane >> 4, n = lane & 15;
    bf16x8 b0 = *(const bf16x8*)(Wbp + (((wv * 2 + 0) * 4 + q) * 16 + n) * 8);
    bf16x8 b1 = *(const bf16x8*)(Wbp + (((wv * 2 + 1) * 4 + q) * 16 + n) * 8);
    const float bias = bb[wv * 16 + n];
    float s = 0.0f;
    for (int rt = 0; rt < nt; ++rt) {
      const short* sa = sh1b + (rt * 16 + n) * SH1S + q * 8;
      bf16x8 a0 = *(const bf16x8*)(sa);
      bf16x8 a1 = *(const bf16x8*)(sa + 32);
      f32x4 acc = {0.f, 0.f, 0.f, 0.f};
      acc = __builtin_amdgcn_mfma_f32_16x16x32_bf16(a0, b0, acc, 0, 0, 0);
      acc = __builtin_amdgcn_mfma_f32_16x16x32_bf16(a1, b1, acc, 0, 0, 0);
#pragma unroll
      for (int reg = 0; reg < 4; ++reg) {
        const int row = rt * 16 + q * 4 + reg;
        const float v = fmaxf(acc[reg] + bias, 0.0f);
        s += (row < c) ? v : 0.0f;
      }
    }
    s += __shfl_down(s, 32);
    s += __shfl_down(s, 16);
    if (lane < 16) xrow[wv * 16 + lane] = s;
  } else {
    if (lane < 16) xrow[wv * 16 + lane] = 0.0f;
  }
}

// ---- shared phase A: gather e (bf16 LDS), P=E@We via MFMA, h1 -> sh1b ----
__device__ __forceinline__ void phaseA(
    int i, int c, const int* s_j, const float* __restrict__ e,
    const float* __restrict__ U, const float* __restrict__ V,
    const short* __restrict__ Wep, short (*esb)[DE], short* sh1b,
    int tid, int lane, int wv)
{
  // gather e rows -> bf16 LDS: 8 threads per slot (32 floats each)
  for (int slot = tid >> 3; slot < c; slot += 32) {
    const int j = s_j[slot];
    float4 f = ((const float4*)(e + ((size_t)i * NN + j) * DE))[tid & 7];
    short4 s4 = { f2b(f.x), f2b(f.y), f2b(f.z), f2b(f.w) };
    *(short4*)(&esb[slot][(tid & 7) * 4]) = s4;
  }

  const int q = lane >> 4, n = lane & 15;
  const int ch = wv * 16 + n;
  // B-frag: We[32x64] col-tile wv (single K-block, K=32)
  bf16x8 bwe = *(const bf16x8*)(Wep + ((wv * 4 + q) * 16 + n) * 8);
  const float u_ch = (c > 0) ? U[(i << 6) + ch] : 0.0f;
  __syncthreads();   // esb visible

  const int nt = (c + 15) >> 4;
  for (int rt = 0; rt < nt; ++rt) {
    bf16x8 a = *(const bf16x8*)(&esb[rt * 16 + n][q * 8]);
    f32x4 P = {0.f, 0.f, 0.f, 0.f};
    P = __builtin_amdgcn_mfma_f32_16x16x32_bf16(a, bwe, P, 0, 0, 0);
#pragma unroll
    for (int reg = 0; reg < 4; ++reg) {
      const int slot = rt * 16 + q * 4 + reg;
      short val = 0;
      if (slot < c) {
        const int j = s_j[slot];
        val = f2b(fmaxf(u_ch + V[(j << 6) + ch] + P[reg], 0.0f));
      }
      sh1b[slot * SH1S + ch] = val;   // C-layout -> A-layout store (b16)
    }
  }
  __syncthreads();   // sh1b visible
}

// ---- K1: scan + U1/V1 + weight packing (no e access) ----
__global__ __launch_bounds__(256) void scan_kernel(
    const float* __restrict__ A, const float* __restrict__ x,
    const float* __restrict__ W, const float* __restrict__ bias,   // W1a,b1a
    const float* __restrict__ We1, const float* __restrict__ We2,
    const float* __restrict__ Wb1, const float* __restrict__ Wb2,
    int* __restrict__ cnt, int* __restrict__ jl,
    float* __restrict__ U, float* __restrict__ V,
    short* __restrict__ Wbp1, short* __restrict__ Wbp2,
    short* __restrict__ We1p, short* __restrict__ We2p)
{
  const int i = blockIdx.x;
  const int tid = threadIdx.x;
  __shared__ int s_cnt;
  __shared__ int s_j[CAP];
  __shared__ float sx[64];
  __shared__ float su[4][64], sv[4][64];

  if (tid == 0) s_cnt = 0;
  __syncthreads();
  if (tid < 64) sx[tid] = x[i * 64 + tid];
  if (tid < NN / 4) {
    float4 a = ((const float4*)(A + i * NN))[tid];
    if (a.x != 0.0f) { int p = atomicAdd(&s_cnt, 1); if (p < CAP) s_j[p] = tid * 4 + 0; }
    if (a.y != 0.0f) { int p = atomicAdd(&s_cnt, 1); if (p < CAP) s_j[p] = tid * 4 + 1; }
    if (a.z != 0.0f) { int p = atomicAdd(&s_cnt, 1); if (p < CAP) s_j[p] = tid * 4 + 2; }
    if (a.w != 0.0f) { int p = atomicAdd(&s_cnt, 1); if (p < CAP) s_j[p] = tid * 4 + 3; }
  }

  if (i < 2) {
    // pack Wb[64x64] -> B-frag order (2 K-blocks of 32)
    const float* srcb = (i == 0) ? Wb1 : Wb2;
    short* dstb = (i == 0) ? Wbp1 : Wbp2;
    for (int L = tid; L < 4096; L += 256) {
      const int j = L & 7, n = (L >> 3) & 15, quad = (L >> 7) & 3;
      const int kb = (L >> 9) & 1, ct = L >> 10;
      dstb[L] = f2b(srcb[(kb * 32 + quad * 8 + j) * 64 + ct * 16 + n]);
    }
    // pack We[32x64] -> B-frag order (single K-block)
    const float* srce = (i == 0) ? We1 : We2;
    short* dste = (i == 0) ? We1p : We2p;
    for (int L = tid; L < 2048; L += 256) {
      const int j = L & 7, n = (L >> 3) & 15, q = (L >> 7) & 3, ct = L >> 9;
      dste[L] = f2b(srce[(q * 8 + j) * 64 + ct * 16 + n]);
    }
  }
  __syncthreads();
  const int c = min(s_cnt, CAP);

  const int c64 = tid & 63, sg = tid >> 6;
  {  // U1/V1 partials
    float u = 0.0f, v = 0.0f;
#pragma unroll
    for (int t = 0; t < 16; ++t) {
      const int d = sg * 16 + t;
      const float xv = sx[d];
      const float wxi = W[d * 64 + c64];
      const float wxj = W[(64 + d) * 64 + c64];
      u = fmaf(xv, wxi - wxj, u);
      v = fmaf(xv, wxj, v);
    }
    su[sg][c64] = u; sv[sg][c64] = v;
  }
  __syncthreads();

  if (tid < 64) {
    U[i * 64 + tid] = su[0][tid] + su[1][tid] + su[2][tid] + su[3][tid] + bias[tid];
    V[i * 64 + tid] = sv[0][tid] + sv[1][tid] + sv[2][tid] + sv[3][tid];
  }
  if (tid == 0) cnt[i] = c;
  for (int t = tid; t < c; t += 256) jl[(i << 7) + t] = s_j[t];
}

// ---- K2: conv1 (MFMA phase A) + U2/V2 ----
__global__ __launch_bounds__(256) void conv1uv2_kernel(
    const int* __restrict__ cnt, const int* __restrict__ jl,
    const float* __restrict__ e,
    const float* __restrict__ U1, const float* __restrict__ V1,
    const short* __restrict__ We1p, const short* __restrict__ Wbp1,
    const float* __restrict__ b1b,
    const float* __restrict__ W2a, const float* __restrict__ b2a,
    float* __restrict__ U2, float* __restrict__ V2)
{
  const int i = blockIdx.x;
  const int tid = threadIdx.x, lane = tid & 63, wv = tid >> 6;
  __shared__ __align__(16) short esb[CAP][DE];      // 8 KB bf16 e rows
  __shared__ __align__(16) short sh1b[CAP * SH1S];  // 18 KB
  __shared__ int s_j[CAP];
  __shared__ float xrow[64];
  __shared__ float su[4][64], sv[4][64];

  const int c = cnt[i];
  for (int t = tid; t < c; t += 256) s_j[t] = jl[(i << 7) + t];
  __syncthreads();

  phaseA(i, c, s_j, e, U1, V1, We1p, esb, sh1b, tid, lane, wv);
  phaseB(sh1b, Wbp1, b1b, xrow, c, lane, wv);
  __syncthreads();

  // U2/V2 GEMV from xrow
  const int c64 = tid & 63, qr = tid >> 6;
  {
    float u = 0.0f, v = 0.0f;
#pragma unroll
    for (int t = 0; t < 16; ++t) {
      const int d = qr * 16 + t;
      const float xv = xrow[d];
      const float wxi = W2a[d * 64 + c64];
      const float wxj = W2a[(64 + d) * 64 + c64];
      u = fmaf(xv, wxi - wxj, u);
      v = fmaf(xv, wxj, v);
    }
    su[qr][c64] = u; sv[qr][c64] = v;
  }
  __syncthreads();
  if (tid < 64) {
    U2[i * 64 + tid] = su[0][tid] + su[1][tid] + su[2][tid] + su[3][tid] + b2a[tid];
    V2[i * 64 + tid] = sv[0][tid] + sv[1][tid] + sv[2][tid] + sv[3][tid];
  }
}

// ---- K3: conv2 (MFMA phase A, e re-gathered warm) + MLP head ----
__global__ __launch_bounds__(256) void conv2head_kernel(
    const int* __restrict__ cnt, const int* __restrict__ jl,
    const float* __restrict__ e,
    const float* __restrict__ U2, const float* __restrict__ V2,
    const short* __restrict__ We2p, const short* __restrict__ Wbp2,
    const float* __restrict__ b2b,
    const float* __restrict__ W3, const float* __restrict__ b3,
    const float* __restrict__ W4, const float* __restrict__ b4,
    float* __restrict__ out)
{
  const int i = blockIdx.x;
  const int tid = threadIdx.x, lane = tid & 63, wv = tid >> 6;
  __shared__ __align__(16) short esb[CAP][DE];
  __shared__ __align__(16) short sh1b[CAP * SH1S];
  __shared__ int s_j[CAP];
  __shared__ float xrow[64];
  __shared__ float sred[2];

  const int c = cnt[i];
  for (int t = tid; t < c; t += 256) s_j[t] = jl[(i << 7) + t];
  __syncthreads();

  phaseA(i, c, s_j, e, U2, V2, We2p, esb, sh1b, tid, lane, wv);
  phaseB(sh1b, Wbp2, b2b, xrow, c, lane, wv);
  __syncthreads();

  // head: relu(xrow @ W3 + b3) @ W4 + b4 -> sigmoid
  if (tid < 128) {
    float p = b3[tid];
#pragma unroll
    for (int cc = 0; cc < 64; ++cc) p = fmaf(xrow[cc], W3[cc * 128 + tid], p);
    p = fmaxf(p, 0.0f);
    float v = p * W4[tid];
    v += __shfl_down(v, 32);
    v += __shfl_down(v, 16);
    v += __shfl_down(v, 8);
    v += __shfl_down(v, 4);
    v += __shfl_down(v, 2);
    v += __shfl_down(v, 1);
    if (lane == 0) sred[wv] = v;
  }
  __syncthreads();
  if (tid == 0) {
    const float z = sred[0] + sred[1] + b4[0];
    out[i] = 1.0f / (1.0f + expf(-z));
  }
}

extern "C" void kernel_launch(void* const* d_in, const int* in_sizes, int n_in,
                              void* d_out, int out_size, void* d_ws, size_t ws_size,
                              hipStream_t stream) {
  const float* A   = (const float*)d_in[0];
  const float* x   = (const float*)d_in[1];
  const float* e   = (const float*)d_in[2];
  const float* W1a = (const float*)d_in[3];
  const float* b1a = (const float*)d_in[4];
  const float* W1b = (const float*)d_in[5];
  const float* b1b = (const float*)d_in[6];
  const float* W2a = (const float*)d_in[7];
  const float* b2a = (const float*)d_in[8];
  const float* W2b = (const float*)d_in[9];
  const float* b2b = (const float*)d_in[10];
  const float* W3  = (const float*)d_in[11];
  const float* b3  = (const float*)d_in[12];
  const float* W4  = (const float*)d_in[13];
  const float* b4  = (const float*)d_in[14];
  float* out = (float*)d_out;

  // ws: [cnt | jl | U1 V1 U2 V2 | Wbp1 Wbp2 We1p We2p]
  int*   cnt  = (int*)d_ws;
  int*   jl   = cnt + NN;                            // 768*128
  float* U1   = (float*)(jl + NN * CAP);
  float* V1   = U1 + NN * HH;
  float* U2   = V1 + NN * HH;
  float* V2   = U2 + NN * HH;
  short* Wbp1 = (short*)(V2 + NN * HH);
  short* Wbp2 = Wbp1 + 4096;
  short* We1p = Wbp2 + 4096;
  short* We2p = We1p + 2048;

  scan_kernel<<<NN, 256, 0, stream>>>(A, x, W1a, b1a,
                                      W1a + 128 * HH, W2a + 128 * HH,
                                      W1b, W2b,
                                      cnt, jl, U1, V1, Wbp1, Wbp2, We1p, We2p);
  conv1uv2_kernel<<<NN, 256, 0, stream>>>(cnt, jl, e, U1, V1, We1p, Wbp1, b1b,
                                          W2a, b2a, U2, V2);
  conv2head_kernel<<<NN, 256, 0, stream>>>(cnt, jl, e, U2, V2, We2p, Wbp2, b2b,
                                           W3, b3, W4, b4, out);
}

// Round 16
// 146.388 us; speedup vs baseline: 1.1151x; 1.0240x over previous
//
#include <hip/hip_runtime.h>
#include <math.h>

// Sparse EdgeConvE round 16: scan fused into K2 (removes cnt->jl cold chain);
// K1 = UV1 + weight packs only (192x4-row blocks). 3 dispatches.
//   h1 = relu( U[i] + V[j] + e_ij @ We ),  U = x@(Wxi-Wxj)+ba, V = x@Wxj
//   out[i] = sum_j relu( h1 @ Wb + bb )
// K1: U1/V1 (4 rows/block); blocks 192/193 pack Wb/We to bf16 B-frag order.
// K2: scan A row -> s_j (LDS); write cnt/jl (for K3, L2-warm); gather e ->
//     bf16 LDS; P=E@We1 (1 MFMA/row-tile); h1 in C-layout; phase B MFMA ->
//     x1 row; U2/V2 GEMV in-block.
// K3: cnt/jl warm; same phases with We2/U2/V2; W3/W4 head + sigmoid.

#define NN 768
#define FF 64
#define DE 32
#define HH 64
#define CAP 128            // per-row edge capacity (deg ~38 +- 6)
#define SH1S 72            // padded bf16 LDS row stride

using bf16x8 = __attribute__((ext_vector_type(8))) short;
using f32x4  = __attribute__((ext_vector_type(4))) float;

__device__ __forceinline__ short f2b(float f) {
  unsigned u = __float_as_uint(f);
  return (short)((u + 0x7fffu + ((u >> 16) & 1u)) >> 16);   // RNE
}

// ---- phase B (shared): H1[cpad x 64]bf16 @ Wb -> xrow[64], masked row sum ----
__device__ __forceinline__ void phaseB(
    const short* sh1b, const short* __restrict__ Wbp,
    const float* __restrict__ bb, float* xrow, int c, int lane, int wv)
{
  if (c > 0) {
    const int nt = (c + 15) >> 4;
    const int q = lane >> 4, n = lane & 15;
    bf16x8 b0 = *(const bf16x8*)(Wbp + (((wv * 2 + 0) * 4 + q) * 16 + n) * 8);
    bf16x8 b1 = *(const bf16x8*)(Wbp + (((wv * 2 + 1) * 4 + q) * 16 + n) * 8);
    const float bias = bb[wv * 16 + n];
    float s = 0.0f;
    for (int rt = 0; rt < nt; ++rt) {
      const short* sa = sh1b + (rt * 16 + n) * SH1S + q * 8;
      bf16x8 a0 = *(const bf16x8*)(sa);
      bf16x8 a1 = *(const bf16x8*)(sa + 32);
      f32x4 acc = {0.f, 0.f, 0.f, 0.f};
      acc = __builtin_amdgcn_mfma_f32_16x16x32_bf16(a0, b0, acc, 0, 0, 0);
      acc = __builtin_amdgcn_mfma_f32_16x16x32_bf16(a1, b1, acc, 0, 0, 0);
#pragma unroll
      for (int reg = 0; reg < 4; ++reg) {
        const int row = rt * 16 + q * 4 + reg;
        const float v = fmaxf(acc[reg] + bias, 0.0f);
        s += (row < c) ? v : 0.0f;
      }
    }
    s += __shfl_down(s, 32);
    s += __shfl_down(s, 16);
    if (lane < 16) xrow[wv * 16 + lane] = s;
  } else {
    if (lane < 16) xrow[wv * 16 + lane] = 0.0f;
  }
}

// ---- shared phase A: gather e (bf16 LDS), P=E@We via MFMA, h1 -> sh1b ----
__device__ __forceinline__ void phaseA(
    int i, int c, const int* s_j, const float* __restrict__ e,
    const float* __restrict__ U, const float* __restrict__ V,
    const short* __restrict__ Wep, short (*esb)[DE], short* sh1b,
    int tid, int lane, int wv)
{
  for (int slot = tid >> 3; slot < c; slot += 32) {
    const int j = s_j[slot];
    float4 f = ((const float4*)(e + ((size_t)i * NN + j) * DE))[tid & 7];
    short4 s4 = { f2b(f.x), f2b(f.y), f2b(f.z), f2b(f.w) };
    *(short4*)(&esb[slot][(tid & 7) * 4]) = s4;
  }

  const int q = lane >> 4, n = lane & 15;
  const int ch = wv * 16 + n;
  bf16x8 bwe = *(const bf16x8*)(Wep + ((wv * 4 + q) * 16 + n) * 8);
  const float u_ch = (c > 0) ? U[(i << 6) + ch] : 0.0f;
  __syncthreads();   // esb visible

  const int nt = (c + 15) >> 4;
  for (int rt = 0; rt < nt; ++rt) {
    bf16x8 a = *(const bf16x8*)(&esb[rt * 16 + n][q * 8]);
    f32x4 P = {0.f, 0.f, 0.f, 0.f};
    P = __builtin_amdgcn_mfma_f32_16x16x32_bf16(a, bwe, P, 0, 0, 0);
#pragma unroll
    for (int reg = 0; reg < 4; ++reg) {
      const int slot = rt * 16 + q * 4 + reg;
      short val = 0;
      if (slot < c) {
        const int j = s_j[slot];
        val = f2b(fmaxf(u_ch + V[(j << 6) + ch] + P[reg], 0.0f));
      }
      sh1b[slot * SH1S + ch] = val;
    }
  }
  __syncthreads();   // sh1b visible
}

// ---- K1: U1/V1 (4 rows/block, blocks 0..191) + weight packs (192/193) ----
__global__ __launch_bounds__(256) void uvpack_kernel(
    const float* __restrict__ x, const float* __restrict__ W,
    const float* __restrict__ bias,
    const float* __restrict__ We1, const float* __restrict__ We2,
    const float* __restrict__ Wb1, const float* __restrict__ Wb2,
    float* __restrict__ U, float* __restrict__ V,
    short* __restrict__ Wbp1, short* __restrict__ Wbp2,
    short* __restrict__ We1p, short* __restrict__ We2p)
{
  const int b = blockIdx.x;
  const int tid = threadIdx.x;

  if (b >= NN / 4) {   // pack blocks
    const int which = b - NN / 4;       // 0 or 1
    const float* srcb = (which == 0) ? Wb1 : Wb2;
    short* dstb = (which == 0) ? Wbp1 : Wbp2;
    for (int L = tid; L < 4096; L += 256) {
      const int j = L & 7, n = (L >> 3) & 15, quad = (L >> 7) & 3;
      const int kb = (L >> 9) & 1, ct = L >> 10;
      dstb[L] = f2b(srcb[(kb * 32 + quad * 8 + j) * 64 + ct * 16 + n]);
    }
    const float* srce = (which == 0) ? We1 : We2;
    short* dste = (which == 0) ? We1p : We2p;
    for (int L = tid; L < 2048; L += 256) {
      const int j = L & 7, n = (L >> 3) & 15, q = (L >> 7) & 3, ct = L >> 9;
      dste[L] = f2b(srce[(q * 8 + j) * 64 + ct * 16 + n]);
    }
    return;
  }

  const int rr = tid >> 6, c64 = tid & 63;
  const int r = b * 4 + rr;
  __shared__ float sx[4][64];
  sx[rr][c64] = x[r * 64 + c64];
  __syncthreads();
  float u = bias[c64], v = 0.0f;
#pragma unroll
  for (int d = 0; d < 64; ++d) {
    const float xv = sx[rr][d];
    const float wxi = W[d * 64 + c64];
    const float wxj = W[(64 + d) * 64 + c64];
    u = fmaf(xv, wxi - wxj, u);
    v = fmaf(xv, wxj, v);
  }
  U[r * 64 + c64] = u;
  V[r * 64 + c64] = v;
}

// ---- K2: scan + conv1 (MFMA) + U2/V2; writes cnt/jl for K3 ----
__global__ __launch_bounds__(256) void scanconv1_kernel(
    const float* __restrict__ A, const float* __restrict__ e,
    const float* __restrict__ U1, const float* __restrict__ V1,
    const short* __restrict__ We1p, const short* __restrict__ Wbp1,
    const float* __restrict__ b1b,
    const float* __restrict__ W2a, const float* __restrict__ b2a,
    int* __restrict__ cnt, int* __restrict__ jl,
    float* __restrict__ U2, float* __restrict__ V2)
{
  const int i = blockIdx.x;
  const int tid = threadIdx.x, lane = tid & 63, wv = tid >> 6;
  __shared__ int s_cnt;
  __shared__ int s_j[CAP];
  __shared__ __align__(16) short esb[CAP][DE];      // 8 KB
  __shared__ __align__(16) short sh1b[CAP * SH1S];  // 18 KB
  __shared__ float xrow[64];
  __shared__ float su[4][64], sv[4][64];

  if (tid == 0) s_cnt = 0;
  __syncthreads();
  if (tid < NN / 4) {
    float4 a = ((const float4*)(A + i * NN))[tid];
    if (a.x != 0.0f) { int p = atomicAdd(&s_cnt, 1); if (p < CAP) s_j[p] = tid * 4 + 0; }
    if (a.y != 0.0f) { int p = atomicAdd(&s_cnt, 1); if (p < CAP) s_j[p] = tid * 4 + 1; }
    if (a.z != 0.0f) { int p = atomicAdd(&s_cnt, 1); if (p < CAP) s_j[p] = tid * 4 + 2; }
    if (a.w != 0.0f) { int p = atomicAdd(&s_cnt, 1); if (p < CAP) s_j[p] = tid * 4 + 3; }
  }
  __syncthreads();
  const int c = min(s_cnt, CAP);
  if (tid == 0) cnt[i] = c;
  for (int t = tid; t < c; t += 256) jl[(i << 7) + t] = s_j[t];

  phaseA(i, c, s_j, e, U1, V1, We1p, esb, sh1b, tid, lane, wv);
  phaseB(sh1b, Wbp1, b1b, xrow, c, lane, wv);
  __syncthreads();

  // U2/V2 GEMV from xrow
  const int c64 = tid & 63, qr = tid >> 6;
  {
    float u = 0.0f, v = 0.0f;
#pragma unroll
    for (int t = 0; t < 16; ++t) {
      const int d = qr * 16 + t;
      const float xv = xrow[d];
      const float wxi = W2a[d * 64 + c64];
      const float wxj = W2a[(64 + d) * 64 + c64];
      u = fmaf(xv, wxi - wxj, u);
      v = fmaf(xv, wxj, v);
    }
    su[qr][c64] = u; sv[qr][c64] = v;
  }
  __syncthreads();
  if (tid < 64) {
    U2[i * 64 + tid] = su[0][tid] + su[1][tid] + su[2][tid] + su[3][tid] + b2a[tid];
    V2[i * 64 + tid] = sv[0][tid] + sv[1][tid] + sv[2][tid] + sv[3][tid];
  }
}

// ---- K3: conv2 (MFMA phase A, cnt/jl L2-warm) + MLP head ----
__global__ __launch_bounds__(256) void conv2head_kernel(
    const int* __restrict__ cnt, const int* __restrict__ jl,
    const float* __restrict__ e,
    const float* __restrict__ U2, const float* __restrict__ V2,
    const short* __restrict__ We2p, const short* __restrict__ Wbp2,
    const float* __restrict__ b2b,
    const float* __restrict__ W3, const float* __restrict__ b3,
    const float* __restrict__ W4, const float* __restrict__ b4,
    float* __restrict__ out)
{
  const int i = blockIdx.x;
  const int tid = threadIdx.x, lane = tid & 63, wv = tid >> 6;
  __shared__ __align__(16) short esb[CAP][DE];
  __shared__ __align__(16) short sh1b[CAP * SH1S];
  __shared__ int s_j[CAP];
  __shared__ float xrow[64];
  __shared__ float sred[2];

  const int c = cnt[i];
  for (int t = tid; t < c; t += 256) s_j[t] = jl[(i << 7) + t];
  __syncthreads();

  phaseA(i, c, s_j, e, U2, V2, We2p, esb, sh1b, tid, lane, wv);
  phaseB(sh1b, Wbp2, b2b, xrow, c, lane, wv);
  __syncthreads();

  // head: relu(xrow @ W3 + b3) @ W4 + b4 -> sigmoid
  if (tid < 128) {
    float p = b3[tid];
#pragma unroll
    for (int cc = 0; cc < 64; ++cc) p = fmaf(xrow[cc], W3[cc * 128 + tid], p);
    p = fmaxf(p, 0.0f);
    float v = p * W4[tid];
    v += __shfl_down(v, 32);
    v += __shfl_down(v, 16);
    v += __shfl_down(v, 8);
    v += __shfl_down(v, 4);
    v += __shfl_down(v, 2);
    v += __shfl_down(v, 1);
    if (lane == 0) sred[wv] = v;
  }
  __syncthreads();
  if (tid == 0) {
    const float z = sred[0] + sred[1] + b4[0];
    out[i] = 1.0f / (1.0f + expf(-z));
  }
}

extern "C" void kernel_launch(void* const* d_in, const int* in_sizes, int n_in,
                              void* d_out, int out_size, void* d_ws, size_t ws_size,
                              hipStream_t stream) {
  const float* A   = (const float*)d_in[0];
  const float* x   = (const float*)d_in[1];
  const float* e   = (const float*)d_in[2];
  const float* W1a = (const float*)d_in[3];
  const float* b1a = (const float*)d_in[4];
  const float* W1b = (const float*)d_in[5];
  const float* b1b = (const float*)d_in[6];
  const float* W2a = (const float*)d_in[7];
  const float* b2a = (const float*)d_in[8];
  const float* W2b = (const float*)d_in[9];
  const float* b2b = (const float*)d_in[10];
  const float* W3  = (const float*)d_in[11];
  const float* b3  = (const float*)d_in[12];
  const float* W4  = (const float*)d_in[13];
  const float* b4  = (const float*)d_in[14];
  float* out = (float*)d_out;

  // ws: [cnt | jl | U1 V1 U2 V2 | Wbp1 Wbp2 We1p We2p]
  int*   cnt  = (int*)d_ws;
  int*   jl   = cnt + NN;                            // 768*128
  float* U1   = (float*)(jl + NN * CAP);
  float* V1   = U1 + NN * HH;
  float* U2   = V1 + NN * HH;
  float* V2   = U2 + NN * HH;
  short* Wbp1 = (short*)(V2 + NN * HH);
  short* Wbp2 = Wbp1 + 4096;
  short* We1p = Wbp2 + 4096;
  short* We2p = We1p + 2048;

  uvpack_kernel<<<NN / 4 + 2, 256, 0, stream>>>(x, W1a, b1a,
                                                W1a + 128 * HH, W2a + 128 * HH,
                                                W1b, W2b,
                                                U1, V1, Wbp1, Wbp2, We1p, We2p);
  scanconv1_kernel<<<NN, 256, 0, stream>>>(A, e, U1, V1, We1p, Wbp1, b1b,
                                           W2a, b2a, cnt, jl, U2, V2);
  conv2head_kernel<<<NN, 256, 0, stream>>>(cnt, jl, e, U2, V2, We2p, Wbp2, b2b,
                                           W3, b3, W4, b4, out);
}